// Round 10
// baseline (288.007 us; speedup 1.0000x reference)
//
#include <hip/hip_runtime.h>
#include <hip/hip_bf16.h>
#include <math.h>

// Problem constants
constexpr int B_ = 2, T_ = 2048, C_ = 1024, NH_ = 16, HS_ = 64, BD_ = 16, DELTA_ = 32;
constexpr int M_ = B_ * T_;   // 4096 rows

typedef __bf16 bf16_t;
typedef __bf16 bf16x8 __attribute__((ext_vector_type(8)));
typedef float  f32x4  __attribute__((ext_vector_type(4)));

__device__ __forceinline__ float frcp(float x)  { return __builtin_amdgcn_rcpf(x); }
__device__ __forceinline__ float fexp2(float x) { return __builtin_amdgcn_exp2f(x); }
__device__ __forceinline__ float rlane(float v, int l) {
    return __builtin_bit_cast(float, __builtin_amdgcn_readlane(__builtin_bit_cast(int, v), l));
}

// tanh-gelu, division-free:  gelu(x) = x - x * rcp(exp2(c1*x + c2*x^3) + 1)
__device__ __forceinline__ float gelu_f(float x) {
    const float x2  = x * x;
    const float arg = x * fmaf(0.10294321f, x2, 2.3022074f);
    const float e   = fexp2(arg);
    const float r   = frcp(e + 1.0f);
    return x - x * r;
}
constexpr float LOG2E = 1.4426950409f;

// ---------------------------------------------------------------------------
// convert fp32 -> bf16
// ---------------------------------------------------------------------------
__global__ __launch_bounds__(256) void convert_bf16_kernel(
    const float* __restrict__ in, bf16_t* __restrict__ out, int n)
{
    const int i = (blockIdx.x * 256 + threadIdx.x) * 8;
    if (i >= n) return;
    const float4 v0 = *(const float4*)(in + i);
    const float4 v1 = *(const float4*)(in + i + 4);
    bf16x8 o;
    o[0] = (bf16_t)v0.x; o[1] = (bf16_t)v0.y; o[2] = (bf16_t)v0.z; o[3] = (bf16_t)v0.w;
    o[4] = (bf16_t)v1.x; o[5] = (bf16_t)v1.y; o[6] = (bf16_t)v1.z; o[7] = (bf16_t)v1.w;
    *(bf16x8*)(out + i) = o;
}

// ---------------------------------------------------------------------------
// fused transpose+convert of the three weight matrices (z selects matrix)
// ---------------------------------------------------------------------------
__global__ __launch_bounds__(256) void transpose3_kernel(
    const float* __restrict__ w_val, const float* __restrict__ w_cproj,
    const float* __restrict__ w_disp,
    bf16_t* __restrict__ wvT, bf16_t* __restrict__ wcT, bf16_t* __restrict__ wdT)
{
    const int z = blockIdx.z;
    const float* in; bf16_t* out; int K = 1024, N = 1024;
    if (z == 0)      { in = w_val;   out = wvT; }
    else if (z == 1) { in = w_cproj; out = wcT; }
    else             { in = w_disp;  out = wdT; N = 256; if (blockIdx.x >= 8) return; }

    __shared__ float tile[32][33];
    const int n0 = blockIdx.x * 32, k0 = blockIdx.y * 32;
    const int tx = threadIdx.x & 31, ty = threadIdx.x >> 5;
    #pragma unroll
    for (int i = 0; i < 4; ++i)
        tile[ty + 8 * i][tx] = in[(size_t)(k0 + ty + 8 * i) * N + n0 + tx];
    __syncthreads();
    #pragma unroll
    for (int i = 0; i < 4; ++i)
        out[(size_t)(n0 + ty + 8 * i) * K + k0 + tx] = (bf16_t)tile[tx][ty + 8 * i];
}

// ---------------------------------------------------------------------------
// bf16 MFMA GEMM core. Tile 128x64, BK=64 (two 32-col LDS planes per buffer ->
// 16 MFMAs per barrier-pair, half the vmcnt(0)+barrier drains of BK=32).
// Double-buffered global_load_lds staging. OutT = float or bf16.
// ---------------------------------------------------------------------------
__device__ __forceinline__ void gload16(const void* g, void* l) {
    __builtin_amdgcn_global_load_lds(
        (__attribute__((address_space(1))) void*)(g),
        (__attribute__((address_space(3))) void*)(l), 16, 0, 0);
}

#define GBM 128
#define GBN 64

template<typename OutT>
__device__ __forceinline__ void gemm_core(
    bf16_t (*Al)[2][GBM][32], bf16_t (*Bl)[2][GBN][32],
    const bf16_t* __restrict__ A, const bf16_t* __restrict__ Bt,
    const float* __restrict__ bias, OutT* __restrict__ C,
    int N, int K, int bm, int bn)
{
    const int tid  = threadIdx.x;
    const int lane = tid & 63;
    const int w    = tid >> 6;
    const int wr   = w >> 1, wc = w & 1;       // 2x2 waves, wave tile 64x32

    // staging lane map: 16 rows x 32 cols per gload16 (64 lanes x 16B)
    const int lrow = lane >> 2;          // 0..15
    const int lcol = (lane & 3) * 8;     // bf16 elems
    const bf16_t* Ab = A  + (size_t)(bm + w * 32 + lrow) * K + lcol;
    const bf16_t* Bb = Bt + (size_t)(bn + w * 16 + lrow) * K + lcol;

    auto STAGE = [&](int buf, int k0) {
        gload16(Ab + k0,                    &Al[buf][0][w * 32][0]);
        gload16(Ab + (size_t)16 * K + k0,   &Al[buf][0][w * 32 + 16][0]);
        gload16(Ab + k0 + 32,               &Al[buf][1][w * 32][0]);
        gload16(Ab + (size_t)16 * K + k0 + 32, &Al[buf][1][w * 32 + 16][0]);
        gload16(Bb + k0,                    &Bl[buf][0][w * 16][0]);
        gload16(Bb + k0 + 32,               &Bl[buf][1][w * 16][0]);
    };

    f32x4 acc[4][2] = {};
    const int nt = K / 64;
    int cur = 0;

    STAGE(0, 0);
    __syncthreads();

    for (int t = 0; t < nt; ++t) {
        if (t + 1 < nt) STAGE(cur ^ 1, (t + 1) * 64);   // prefetch overlaps MFMA
        #pragma unroll
        for (int kk = 0; kk < 2; ++kk) {
            bf16x8 af[4], bfr[2];
            #pragma unroll
            for (int i = 0; i < 4; ++i)
                af[i] = *(const bf16x8*)&Al[cur][kk][wr * 64 + i * 16 + (lane & 15)][(lane >> 4) * 8];
            #pragma unroll
            for (int j = 0; j < 2; ++j)
                bfr[j] = *(const bf16x8*)&Bl[cur][kk][wc * 32 + j * 16 + (lane & 15)][(lane >> 4) * 8];
            #pragma unroll
            for (int i = 0; i < 4; ++i)
                #pragma unroll
                for (int j = 0; j < 2; ++j)
                    acc[i][j] = __builtin_amdgcn_mfma_f32_16x16x32_bf16(af[i], bfr[j], acc[i][j], 0, 0, 0);
        }
        __syncthreads();   // drains vmcnt (next tile resident) + protects LDS
        cur ^= 1;
    }

    #pragma unroll
    for (int i = 0; i < 4; ++i) {
        const int r0 = bm + wr * 64 + i * 16 + (lane >> 4) * 4;
        #pragma unroll
        for (int j = 0; j < 2; ++j) {
            const int c = bn + wc * 32 + j * 16 + (lane & 15);
            const float bv = bias[c];
            OutT* cp = C + (size_t)r0 * N + c;
            #pragma unroll
            for (int q = 0; q < 4; ++q)
                cp[(size_t)q * N] = (OutT)(acc[i][j][q] + bv);
        }
    }
}

// generic GEMM (cproj): grid (N/64, M/128), XCD-chunked swizzle
template<typename OutT>
__global__ __launch_bounds__(256) void gemm_bf16_db(
    const bf16_t* __restrict__ A, const bf16_t* __restrict__ Bt,
    const float* __restrict__ bias, OutT* __restrict__ C,
    int M, int N, int K)
{
    __shared__ __align__(16) bf16_t Al[2][2][GBM][32];
    __shared__ __align__(16) bf16_t Bl[2][2][GBN][32];
    const int gx  = gridDim.x;
    const int nwg = gx * gridDim.y;
    const int bid = blockIdx.y * gx + blockIdx.x;
    const int wid = (bid & 7) * (nwg >> 3) + (bid >> 3);   // nwg % 8 == 0
    const int bx  = wid % gx, by = wid / gx;
    gemm_core<OutT>(Al, Bl, A, Bt, bias, C, N, K, by * GBM, bx * GBN);
}

// fused val+disp GEMM: grid (20, 32). bx<16 -> val (bf16 out), bx>=16 -> disp (f32)
__global__ __launch_bounds__(256) void gemm_dv_fused(
    const bf16_t* __restrict__ A,
    const bf16_t* __restrict__ wvT, const bf16_t* __restrict__ wdT,
    const float* __restrict__ b_val, const float* __restrict__ b_disp,
    bf16_t* __restrict__ valb, float* __restrict__ disp)
{
    __shared__ __align__(16) bf16_t Al[2][2][GBM][32];
    __shared__ __align__(16) bf16_t Bl[2][2][GBN][32];
    const int gx  = 20;
    const int nwg = 640;
    const int bid = blockIdx.y * gx + blockIdx.x;
    const int wid = (bid & 7) * (nwg >> 3) + (bid >> 3);   // 640 % 8 == 0, bijective
    const int bx  = wid % gx, by = wid / gx;
    if (bx < 16)
        gemm_core<bf16_t>(Al, Bl, A, wvT, b_val, valb, 1024, 1024, by * GBM, bx * GBN);
    else
        gemm_core<float>(Al, Bl, A, wdT, b_disp, disp, 256, 1024, by * GBM, (bx - 16) * GBN);
}

// ---------------------------------------------------------------------------
// precomp: block = (b, h, 128-t tile). Stage disp halo slice in LDS once.
// ---------------------------------------------------------------------------
#define PCT 128
__global__ __launch_bounds__(256) void precomp_kernel(
    const float* __restrict__ disp,
    const float* __restrict__ w_state, const float* __restrict__ b_state,
    const float* __restrict__ w_strain, const float* __restrict__ b_strain,
    const float* __restrict__ w_state_i, const float* __restrict__ w_state_j,
    const float* __restrict__ w_damage,
    float* __restrict__ P1, float* __restrict__ Q1, float* __restrict__ P2)
{
    __shared__ float s_d[PCT + 31][20];
    __shared__ float s_mv[PCT][20];
    __shared__ float s_st[PCT][20];
    __shared__ float s_wst[16][16], s_wstr[16][16], s_wsi[16][16], s_wsj[16][16], s_wdmg[16][16];
    __shared__ float s_bst[16], s_bstr[16];

    const int bid = blockIdx.x;
    const int tile = bid & (T_ / PCT - 1);
    const int h    = (bid >> 4) & 15;
    const int b    = bid >> 8;
    const int t0   = tile * PCT;
    const int tid  = threadIdx.x;

    s_wst[tid >> 4][tid & 15]  = w_state[tid];
    s_wstr[tid >> 4][tid & 15] = w_strain[tid];
    s_wsi[tid >> 4][tid & 15]  = w_state_i[tid];
    s_wsj[tid >> 4][tid & 15]  = w_state_j[tid];
    s_wdmg[tid >> 4][tid & 15] = w_damage[tid];
    if (tid < 16) { s_bst[tid] = b_state[tid]; s_bstr[tid] = b_strain[tid]; }

    for (int it = tid; it < (PCT + 31) * 4; it += 256) {
        const int row = it >> 2, q = it & 3;
        int rg = t0 - 31 + row; if (rg < 0) rg = 0;
        *(float4*)&s_d[row][q * 4] =
            *(const float4*)(disp + (size_t)(b * T_ + rg) * 256 + h * 16 + q * 4);
    }
    __syncthreads();

    #pragma unroll
    for (int p = 0; p < 8; ++p) {
        const int it = p * 256 + tid;
        const int tl = it >> 4, e = it & 15;
        const int t = t0 + tl;
        const int dlo = max(0, 31 - t);
        float s = 0.0f;
        for (int d = dlo; d < 32; ++d) s += s_d[tl + d][e];
        s_mv[tl][e] = s * frcp((float)(32 - dlo)) - s_d[tl + 31][e];
    }
    __syncthreads();

    #pragma unroll
    for (int p = 0; p < 8; ++p) {
        const int it = p * 256 + tid;
        const int tl = it >> 4, e = it & 15;
        float a = s_bst[e];
        #pragma unroll
        for (int k = 0; k < 16; ++k) a += s_mv[tl][k] * s_wst[k][e];
        s_st[tl][e] = a;
    }
    __syncthreads();

    #pragma unroll
    for (int p = 0; p < 8; ++p) {
        const int it = p * 256 + tid;
        const int tl = it >> 4, e = it & 15;
        float d1 = 0.0f, p2 = 0.0f, sj = 0.0f, si = 0.0f;
        #pragma unroll
        for (int k = 0; k < 16; ++k) {
            const float dv = s_d[tl + 31][k];
            const float sv = s_st[tl][k];
            d1 += dv * s_wstr[k][e];
            p2 += dv * s_wdmg[k][e];
            sj += sv * s_wsj[k][e];
            si += sv * s_wsi[k][e];
        }
        const size_t o = (size_t)(b * T_ + t0 + tl) * 256 + h * 16 + e;
        P1[o] = d1 + sj;
        Q1[o] = s_bstr[e] + si - d1;
        P2[o] = p2;
    }
}

// ---------------------------------------------------------------------------
// attn v5: block = (b, h, 64-t tile). LDS holds only sP1/sP2/sQ1/relw (23 KB
// -> 6 blocks/CU). PV reads val (bf16) straight from global (12 KB/block slice,
// L1/L2-resident, coalesced 128B rows). tile==0 uses the MASKED variant.
// ---------------------------------------------------------------------------
template<bool MASKED>
__device__ __forceinline__ void attn_body(
    const float (&sP1)[95][20], const float (&sP2)[95][20],
    const float (&sQ1)[64][20], const float (&s_relw)[32][20],
    const float* s_wb, const float* s_wd, const float* s_bd,
    int t0, int w, int lane, int half, int d,
    float bb, float bdo,
    const bf16_t* __restrict__ vbase,   // valb + b*T*1024 + h*64 + lane
    bf16_t* __restrict__ obase)         // att  + (b*T+t0)*1024 + h*64 + lane
{
    float wv[8];

    // ---- scoring: wave w handles pairs 8w..8w+7 (t_local 16w..16w+15) ----
    #pragma unroll
    for (int pp = 0; pp < 8; ++pp) {
        const int p  = (w << 3) + pp;
        const int tl = (p << 1) + half;
        const int i  = tl + d;
        const bool valid = MASKED ? ((t0 - 31 + i) >= 0) : true;

        float bacc = 0.0f, dacc = 0.0f;
        #pragma unroll
        for (int q = 0; q < 4; ++q) {
            const float4 q1  = *(const float4*)&sQ1[tl][q * 4];
            const float4 p2t = *(const float4*)&sP2[tl + 31][q * 4];
            const float4 p1r = *(const float4*)&sP1[i][q * 4];
            const float4 p2r = *(const float4*)&sP2[i][q * 4];
            const float4 rw  = *(const float4*)&s_relw[d][q * 4];
            bacc += gelu_f(p1r.x + q1.x + rw.x) * s_wb[4 * q + 0];
            bacc += gelu_f(p1r.y + q1.y + rw.y) * s_wb[4 * q + 1];
            bacc += gelu_f(p1r.z + q1.z + rw.z) * s_wb[4 * q + 2];
            bacc += gelu_f(p1r.w + q1.w + rw.w) * s_wb[4 * q + 3];
            dacc += gelu_f(p2r.x - p2t.x + s_bd[4 * q + 0]) * s_wd[4 * q + 0];
            dacc += gelu_f(p2r.y - p2t.y + s_bd[4 * q + 1]) * s_wd[4 * q + 1];
            dacc += gelu_f(p2r.z - p2t.z + s_bd[4 * q + 2]) * s_wd[4 * q + 2];
            dacc += gelu_f(p2r.w - p2t.w + s_bd[4 * q + 3]) * s_wd[4 * q + 3];
        }

        float logit;
        const float damage = frcp(1.0f + fexp2(-LOG2E * (dacc + bdo)));
        logit = bacc + bb - 10.0f * damage;
        if (MASKED && !valid) logit = -INFINITY;

        float m = logit;
        #pragma unroll
        for (int off = 16; off; off >>= 1) m = fmaxf(m, __shfl_xor(m, off, 32));
        float pe = fexp2(LOG2E * (logit - m));
        if (MASKED && !valid) pe = 0.0f;
        float ss = pe;
        #pragma unroll
        for (int off = 16; off; off >>= 1) ss += __shfl_xor(ss, off, 32);
        wv[pp] = pe * frcp(ss);
    }

    // ---- PV: lane = e; weights broadcast via readlane; val from global ----
    #pragma unroll
    for (int pp = 0; pp < 8; ++pp) {
        const int tl0 = (w << 4) + (pp << 1);
        float acc0 = 0.0f, acc1 = 0.0f;
        #pragma unroll
        for (int j = 0; j < 33; ++j) {
            int row = t0 + tl0 - 31 + j;
            if (MASKED) row = row < 0 ? 0 : row;   // weight is 0 there; keep addr in-bounds
            const float v = (float)vbase[(size_t)row * 1024];
            if (j < 32) acc0 += rlane(wv[pp], j) * v;
            if (j >= 1) acc1 += rlane(wv[pp], 31 + j) * v;
        }
        obase[(size_t)tl0 * 1024]       = (bf16_t)acc0;
        obase[(size_t)(tl0 + 1) * 1024] = (bf16_t)acc1;
    }
}

__global__ __launch_bounds__(256, 6) void attn_kernel(
    const float* __restrict__ P1, const float* __restrict__ Q1,
    const float* __restrict__ P2, const bf16_t* __restrict__ valb,
    const float* __restrict__ rel_pos_emb, const float* __restrict__ w_pos,
    const float* __restrict__ w_bond_out, const float* __restrict__ b_bond_out,
    const float* __restrict__ b_damage,
    const float* __restrict__ w_damage_out, const float* __restrict__ b_damage_out,
    bf16_t* __restrict__ att)
{
    __shared__ float sP1[95][20], sP2[95][20], sQ1[64][20];
    __shared__ float s_relw[32][20];
    __shared__ float s_wb[16], s_wd[16], s_bd[16];

    const int tid  = threadIdx.x;
    const int bid  = blockIdx.x;
    const int tile = bid & 31;
    const int h    = (bid >> 5) & 15;
    const int b    = bid >> 9;
    const int t0   = tile * 64;

    for (int it = tid; it < 95 * 4; it += 256) {
        const int row = it >> 2, q = it & 3;
        int rg = t0 - 31 + row; if (rg < 0) rg = 0;
        const size_t o = (size_t)(b * T_ + rg) * 256 + h * 16 + q * 4;
        *(float4*)&sP1[row][q * 4] = *(const float4*)(P1 + o);
        *(float4*)&sP2[row][q * 4] = *(const float4*)(P2 + o);
    }
    {
        const int row = tid >> 2, q = tid & 3;
        *(float4*)&sQ1[row][q * 4] =
            *(const float4*)(Q1 + (size_t)(b * T_ + t0 + row) * 256 + h * 16 + q * 4);
    }
    {
        for (int it = tid; it < 512; it += 256) {
            const int dd = it >> 4, ee = it & 15;
            float a = 0.0f;
            #pragma unroll
            for (int k = 0; k < 16; ++k) a += rel_pos_emb[dd * 16 + k] * w_pos[k * 16 + ee];
            s_relw[dd][ee] = a;
        }
        if (tid < 16) {
            s_wb[tid] = w_bond_out[tid];
            s_wd[tid] = w_damage_out[tid];
            s_bd[tid] = b_damage[tid];
        }
    }
    __syncthreads();

    const int lane = tid & 63;
    const int w    = tid >> 6;
    const int half = lane >> 5;
    const int d    = lane & 31;
    const float bb  = b_bond_out[0];
    const float bdo = b_damage_out[0];

    const bf16_t* vbase = valb + (size_t)b * T_ * 1024 + h * 64 + lane;
    bf16_t* obase = att + (size_t)(b * T_ + t0) * 1024 + h * 64 + lane;

    if (tile != 0)
        attn_body<false>(sP1, sP2, sQ1, s_relw, s_wb, s_wd, s_bd,
                         t0, w, lane, half, d, bb, bdo, vbase, obase);
    else
        attn_body<true>(sP1, sP2, sQ1, s_relw, s_wb, s_wd, s_bd,
                        t0, w, lane, half, d, bb, bdo, vbase, obase);
}

// ---------------------------------------------------------------------------
extern "C" void kernel_launch(void* const* d_in, const int* in_sizes, int n_in,
                              void* d_out, int out_size, void* d_ws, size_t ws_size,
                              hipStream_t stream)
{
    const float* x        = (const float*)d_in[0];
    const float* w_disp   = (const float*)d_in[1];
    const float* b_disp   = (const float*)d_in[2];
    const float* w_val    = (const float*)d_in[3];
    const float* b_val    = (const float*)d_in[4];
    const float* rel      = (const float*)d_in[5];
    const float* w_state  = (const float*)d_in[6];
    const float* b_state  = (const float*)d_in[7];
    const float* w_strain = (const float*)d_in[8];
    const float* b_strain = (const float*)d_in[9];
    const float* w_si     = (const float*)d_in[10];
    const float* w_sj     = (const float*)d_in[11];
    const float* w_pos    = (const float*)d_in[12];
    const float* w_bond   = (const float*)d_in[13];
    const float* b_bond   = (const float*)d_in[14];
    const float* w_dmg    = (const float*)d_in[15];
    const float* b_dmg    = (const float*)d_in[16];
    const float* w_dout   = (const float*)d_in[17];
    const float* b_dout   = (const float*)d_in[18];
    const float* w_cproj  = (const float*)d_in[19];
    const float* b_cproj  = (const float*)d_in[20];

    float* out = (float*)d_out;
    float* ws  = (float*)d_ws;

    // layout (R = 1M floats = 4 MB):
    //   [0,R)   disp fp32      [R,2R) P1   [2R,3R) Q1   [3R,4R) P2
    //   [4R,6R) xb / attb bf16 (8 MB)
    //   [6R,8R) wdT | wvT | wcT bf16 (4.5 MB used)
    //   [8R,10R) valb bf16 (8 MB)
    const size_t R = (size_t)M_ * 256;
    float* disp = ws;
    float* P1   = ws + R;
    float* Q1   = ws + 2 * R;
    float* P2   = ws + 3 * R;
    bf16_t* xb   = (bf16_t*)(ws + 4 * R);
    bf16_t* attb = xb;                               // alias: xb dead after dv GEMM
    bf16_t* wdT  = (bf16_t*)(ws + 6 * R);
    bf16_t* wvT  = wdT + (size_t)256 * 1024;
    bf16_t* wcT  = wvT + (size_t)1024 * 1024;
    bf16_t* valb = (bf16_t*)(ws + 8 * R);

    convert_bf16_kernel<<<(M_ * C_) / (256 * 8), 256, 0, stream>>>(x, xb, M_ * C_);
    transpose3_kernel<<<dim3(32, 32, 3), 256, 0, stream>>>(w_val, w_cproj, w_disp, wvT, wcT, wdT);

    // fused: valb = bf16(x@w_val + b_val), disp = x@w_disp + b_disp
    gemm_dv_fused<<<dim3(20, 32), 256, 0, stream>>>(xb, wvT, wdT, b_val, b_disp, valb, disp);

    precomp_kernel<<<B_ * NH_ * (T_ / PCT), 256, 0, stream>>>(
        disp, w_state, b_state, w_strain, b_strain, w_si, w_sj, w_dmg, P1, Q1, P2);

    attn_kernel<<<B_ * NH_ * (T_ / 64), 256, 0, stream>>>(
        P1, Q1, P2, valb, rel, w_pos, w_bond, b_bond, b_dmg, w_dout, b_dout, attb);

    // out = att @ w_cproj + b_cproj
    gemm_bf16_db<float><<<dim3(C_ / GBN, M_ / GBM), 256, 0, stream>>>(attb, wcT, b_cproj, out, M_, C_, C_);
}